// Round 1
// baseline (5234.458 us; speedup 1.0000x reference)
//
#include <hip/hip_runtime.h>
#include <hip/hip_bf16.h>
#include <stdint.h>

// LSTM fused pipeline for B=256,S=512,D=256,H=256,O=128 on gfx950.
// Stages:
//  1) k_prep   : pack Wx/Wh (4 gates concat, j=gate*256+h) into MFMA-B-fragment
//                layout bf16; biasj[j] = Wx_b[j]+Wh_b[j].
//  2) k_convx  : x[b][s][d] f32 -> xbf[s][b][d] bf16, XOR-swizzled ((b&7)<<4)
//                so LDS A-fragment reads are bank-conflict-free.
//  3) k_gemm_x : xcat[s][b][j] = bf16( xbf@WxP + biasj + bgate[b] )   (MFMA)
//  4) k_lstm   : 16 WGs x 16 batches, 512 sequential steps. h in LDS (dbuf,
//                swizzled), c in VGPRs, Wh streamed from L2 as B-fragments.
//  5) k_proj   : p = h@Wph^T + b, softmax over O=128.

typedef unsigned short u16;
typedef unsigned int   u32;
typedef __bf16  bf16x8 __attribute__((ext_vector_type(8)));
typedef float   f32x4  __attribute__((ext_vector_type(4)));

union U4 { uint4 u; bf16x8 b; u16 s[8]; };

static __device__ __forceinline__ u16 f2b(float f){
  union { __hip_bfloat16 h; u16 u; } cv; cv.h = __float2bfloat16(f); return cv.u;
}
static __device__ __forceinline__ float b2f(u16 v){
  union { __hip_bfloat16 h; u16 u; } cv; cv.u = v; return __bfloat162float(cv.h);
}
static __device__ __forceinline__ float fsig(float x){
  return __builtin_amdgcn_rcpf(1.0f + __expf(-x));
}
static __device__ __forceinline__ float ftanh(float x){
  float ax = fabsf(x);
  float t  = __expf(-2.0f*ax);
  float r  = (1.0f - t) * __builtin_amdgcn_rcpf(1.0f + t);
  return copysignf(r, x);
}

struct PrepArgs {
  const float* wx[4]; const float* wh[4];
  const float* wxb[4]; const float* whb[4];
};

// ---------------------------------------------------------------- k_prep ----
// Fragment-ready packing: P[jb][kb][lane][e] (16B per lane per frag slot).
// B-frag for mfma_f32_16x16x32_bf16: lane l holds W[jb*16+(l&15)][kb*32+(l>>4)*8+e].
__global__ void k_prep(PrepArgs P, u16* __restrict__ WxP, u16* __restrict__ WhP,
                       float* __restrict__ biasj)
{
  int sIdx = blockIdx.x*256 + threadIdx.x;          // 32768 frag slots
  int lane = sIdx & 63, kb = (sIdx>>6)&7, jb = sIdx>>9;
  int j  = jb*16 + (lane & 15);
  int kbase = kb*32 + ((lane>>4)<<3);
  int gate = j >> 8, jj = j & 255;
  const float* wx = P.wx[gate];
  const float* wh = P.wh[gate];
  U4 ox, oh;
  #pragma unroll
  for (int e=0; e<8; e++){
    ox.s[e] = f2b(wx[jj*256 + kbase + e]);
    oh.s[e] = f2b(wh[jj*256 + kbase + e]);
  }
  *(uint4*)(WxP + (size_t)sIdx*8) = ox.u;
  *(uint4*)(WhP + (size_t)sIdx*8) = oh.u;
  if (sIdx < 1024){
    int g2 = sIdx >> 8, h2 = sIdx & 255;
    biasj[sIdx] = P.wxb[g2][h2] + P.whb[g2][h2];
  }
}

// --------------------------------------------------------------- k_convx ----
// x[b][s][d] f32 -> xbf[s][b][d] bf16, 8 elems (16B) per thread, swizzled dest.
__global__ void k_convx(const float* __restrict__ x, u16* __restrict__ xbf)
{
  int tid = blockIdx.x*256 + threadIdx.x;           // 4,194,304 threads
  int ch = tid & 31;                                // d-chunk (8 elems)
  int b  = (tid>>5) & 255;
  int s  = tid >> 13;
  const float* src = x + ((size_t)b*512 + s)*256 + ch*8;
  float4 f0 = *(const float4*)(src);
  float4 f1 = *(const float4*)(src + 4);
  U4 o;
  o.s[0]=f2b(f0.x); o.s[1]=f2b(f0.y); o.s[2]=f2b(f0.z); o.s[3]=f2b(f0.w);
  o.s[4]=f2b(f1.x); o.s[5]=f2b(f1.y); o.s[6]=f2b(f1.z); o.s[7]=f2b(f1.w);
  u32 byteoff = (u32)(s*256 + b)*512u + (((u32)ch*16u) ^ ((u32)(b&7)<<4));
  *(uint4*)((char*)xbf + byteoff) = o.u;
}

// -------------------------------------------------------------- k_gemm_x ----
// Block: 128 rows (one s, half the batches) x 256 j-cols (one gate), K=256.
// 8 waves (2m x 4n), each wave 64x64, acc 4x4 frags.
__launch_bounds__(512)
__global__ void k_gemm_x(const u16* __restrict__ xbf, const u16* __restrict__ WxP,
                         const float* __restrict__ biasj,
                         const float* __restrict__ bgg, const float* __restrict__ bii,
                         const float* __restrict__ bff, const float* __restrict__ boo,
                         u16* __restrict__ xcat)
{
  __shared__ u16 smA[128*256];                       // 64 KB, swizzled layout
  int tid = threadIdx.x;
  int bid = blockIdx.x;                              // 4096
  int mt = bid >> 2, jt = bid & 3;                   // jt == gate
  int s = mt >> 1, b0 = (mt & 1)*128;

  // stage A tile: linear 64 KB copy (source is pre-swizzled)
  const uint4* srcA = (const uint4*)(xbf + (size_t)(s*256 + b0)*256);
  uint4* dstA = (uint4*)smA;
  #pragma unroll
  for (int i=0; i<8; i++) dstA[tid + i*512] = srcA[tid + i*512];
  __syncthreads();

  int lane = tid & 63, wid = tid >> 6;
  int wm = wid >> 2, wn = wid & 3;
  int r16 = lane & 15, khi = lane >> 4;

  f32x4 acc[4][4] = {};
  #pragma unroll
  for (int kb=0; kb<8; kb++){
    bf16x8 a[4];
    #pragma unroll
    for (int mb=0; mb<4; mb++){
      int row = wm*64 + mb*16 + r16;
      u32 abyte = (u32)row*512u + ((u32)((kb*32 + khi*8)*2) ^ ((u32)(row&7)<<4));
      U4 t; t.u = *(const uint4*)((const char*)smA + abyte);
      a[mb] = t.b;
    }
    #pragma unroll
    for (int nb=0; nb<4; nb++){
      int jbg = jt*16 + wn*4 + nb;
      U4 t; t.u = *(const uint4*)(WxP + (size_t)((jbg*8 + kb)*64 + lane)*8);
      #pragma unroll
      for (int mb=0; mb<4; mb++)
        acc[mb][nb] = __builtin_amdgcn_mfma_f32_16x16x32_bf16(a[mb], t.b, acc[mb][nb], 0,0,0);
    }
  }

  const float* bb = (jt==0) ? bgg : (jt==1) ? bii : (jt==2) ? bff : boo;
  #pragma unroll
  for (int nb=0; nb<4; nb++){
    int j  = jt*256 + wn*64 + nb*16 + r16;
    int hh = j & 255;
    float bj = biasj[j];
    #pragma unroll
    for (int mb=0; mb<4; mb++){
      #pragma unroll
      for (int r=0; r<4; r++){
        int m = wm*64 + mb*16 + khi*4 + r;
        int b = b0 + m;
        float v = acc[mb][nb][r] + bj + bb[b*256 + hh];
        xcat[(u32)(s*256 + b)*1024u + (u32)j] = f2b(v);
      }
    }
  }
}

// ---------------------------------------------------------------- k_lstm ----
// 16 blocks x 1024 threads (16 waves). Block g owns batches [16g,16g+16).
// Wave w owns h-cols [16w,16w+16) for all 4 gates. M=16,N=64,K=256 per wave.
__launch_bounds__(1024)
__global__ void k_lstm(const u16* __restrict__ xcat, const u16* __restrict__ WhP,
                       float* __restrict__ hfin)
{
  __shared__ u16 hb[2][16*256];                      // 16 KB double-buffered h
  int tid = threadIdx.x, lane = tid & 63, w = tid >> 6;
  int b0 = blockIdx.x * 16;
  int r16 = lane & 15, khi = lane >> 4;

  for (int i=tid; i<4096; i+=1024) hb[0][i] = 0;     // h0 = 0
  __syncthreads();

  float c[4] = {0.f,0.f,0.f,0.f};                    // c0 = 0
  int cur = 0;
  const u16* whbase = WhP + lane*8;
  // xcat lane base: j = g*256 + w*16 + r16 ; m = khi*4 + r
  u32 xoff0 = (u32)b0*1024u + (u32)(w*16 + r16) + (u32)(khi*4)*1024u;

  for (int t=0; t<512; t++){
    const u16* xc = xcat + (size_t)t*262144 + xoff0;
    float xv[4][4];
    #pragma unroll
    for (int g=0; g<4; g++)
      #pragma unroll
      for (int r=0; r<4; r++)
        xv[g][r] = b2f(xc[r*1024 + g*256]);

    f32x4 acc[4] = {};
    #pragma unroll
    for (int kb=0; kb<8; kb++){
      u32 abyte = (u32)r16*512u + ((u32)((kb*32 + khi*8)*2) ^ ((u32)(r16&7)<<4));
      U4 ta; ta.u = *(const uint4*)((const char*)hb[cur] + abyte);
      #pragma unroll
      for (int g=0; g<4; g++){
        int jb = g*16 + w;
        U4 tb; tb.u = *(const uint4*)(whbase + (size_t)(jb*8 + kb)*512);
        acc[g] = __builtin_amdgcn_mfma_f32_16x16x32_bf16(ta.b, tb.b, acc[g], 0,0,0);
      }
    }

    #pragma unroll
    for (int r=0; r<4; r++){
      float gp = ftanh(acc[0][r] + xv[0][r]);
      float ip = fsig (acc[1][r] + xv[1][r]);
      float fp = fsig (acc[2][r] + xv[2][r]);
      float op = fsig (acc[3][r] + xv[3][r]);
      c[r] = gp*ip + c[r]*fp;
      float hv = ftanh(c[r]) * op;
      int m = khi*4 + r, col = w*16 + r16;
      u32 wbyte = (u32)m*512u + (((u32)(col*2)) ^ ((u32)(m&7)<<4));
      *(u16*)((char*)hb[cur^1] + wbyte) = f2b(hv);
      if (t == 511) hfin[(b0 + m)*256 + col] = hv;
    }
    __syncthreads();
    cur ^= 1;
  }
}

// ---------------------------------------------------------------- k_proj ----
__global__ void k_proj(const float* __restrict__ hfin, const float* __restrict__ Wph_w,
                       const float* __restrict__ Wph_b, const float* __restrict__ bp,
                       float* __restrict__ out)
{
  __shared__ float hrow[256];
  __shared__ float pbuf[128];
  int b = blockIdx.x, tid = threadIdx.x;             // 128 threads
  hrow[tid]       = hfin[b*256 + tid];
  hrow[tid + 128] = hfin[b*256 + 128 + tid];
  __syncthreads();
  const float* wr = Wph_w + (size_t)tid*256;
  float acc = Wph_b[tid] + bp[b*128 + tid];
  #pragma unroll 8
  for (int k=0; k<256; k++) acc += hrow[k]*wr[k];
  pbuf[tid] = acc;
  __syncthreads();
  float mx = -1e30f;
  for (int i=0; i<128; i++) mx = fmaxf(mx, pbuf[i]);
  float e = __expf(acc - mx);
  __syncthreads();
  pbuf[tid] = e;
  __syncthreads();
  float sum = 0.f;
  for (int i=0; i<128; i++) sum += pbuf[i];
  out[b*128 + tid] = e / sum;
}

// ----------------------------------------------------------------- launch ----
extern "C" void kernel_launch(void* const* d_in, const int* in_sizes, int n_in,
                              void* d_out, int out_size, void* d_ws, size_t ws_size,
                              hipStream_t stream)
{
  (void)in_sizes; (void)n_in; (void)out_size; (void)ws_size;
  const float* x     = (const float*)d_in[0];
  const float* Wph_w = (const float*)d_in[17];
  const float* Wph_b = (const float*)d_in[18];
  const float* bg    = (const float*)d_in[19];
  const float* bi    = (const float*)d_in[20];
  const float* bf    = (const float*)d_in[21];
  const float* bo    = (const float*)d_in[22];
  const float* bp    = (const float*)d_in[23];

  PrepArgs P;
  // gates: g,i,f,o -> input indices (1+4g weights, 3+4g rec, 2+4g bias, 4+4g rec bias)
  for (int g=0; g<4; g++){
    P.wx[g]  = (const float*)d_in[1 + 4*g];
    P.wxb[g] = (const float*)d_in[2 + 4*g];
    P.wh[g]  = (const float*)d_in[3 + 4*g];
    P.whb[g] = (const float*)d_in[4 + 4*g];
  }

  char* ws = (char*)d_ws;
  u16*   xcat  = (u16*)(ws);                                   // 268435456 B
  u16*   xbf   = (u16*)(ws + 268435456);                       //  67108864 B
  u16*   WxP   = (u16*)(ws + 268435456 + 67108864);            //    524288 B
  u16*   WhP   = (u16*)(ws + 268435456 + 67108864 + 524288);   //    524288 B
  float* biasj = (float*)(ws + 268435456 + 67108864 + 1048576);//      4096 B
  float* hfin  = (float*)(ws + 268435456 + 67108864 + 1048576 + 4096); // 262144 B

  k_prep <<<128,   256, 0, stream>>>(P, WxP, WhP, biasj);
  k_convx<<<16384, 256, 0, stream>>>(x, xbf);
  k_gemm_x<<<4096, 512, 0, stream>>>(xbf, WxP, biasj, bg, bi, bf, bo, xcat);
  k_lstm <<<16,   1024, 0, stream>>>(xcat, WhP, hfin);
  k_proj <<<256,   128, 0, stream>>>(hfin, Wph_w, Wph_b, bp, (float*)d_out);
}

// Round 3
// 2389.057 us; speedup vs baseline: 2.1910x; 2.1910x over previous
//
#include <hip/hip_runtime.h>
#include <hip/hip_bf16.h>
#include <stdint.h>

// LSTM fused pipeline for B=256,S=512,D=256,H=256,O=128 on gfx950.
//
// Key idea this round: VGPR-resident recurrent weights.
//   k_lstm: 16 groups (16 batches each) x 4 blocks/group = 64 blocks x 512 thr.
//   Gate columns interleaved jp = hc*4 + gate, so each block owns 64 h-cols
//   with all 4 gates and updates c/h locally (3 intra-quad shuffles).
//   Wave holds its 32 jp-cols x 256 K weight slice in 64 VGPRs (loaded once).
//   h exchanged per step via L2 (hx buffers) + device-scope atomic counter
//   barrier; blocks of a group land on one XCD via bid%8 (perf heuristic).
//   xcat pre-packed into per-(block,step) 8KB blobs -> 1 uint4/thread/step,
//   prefetched one step ahead.

typedef unsigned short u16;
typedef unsigned int   u32;
typedef __bf16  bf16x8 __attribute__((ext_vector_type(8)));
typedef float   f32x4  __attribute__((ext_vector_type(4)));

union U4 { uint4 u; bf16x8 b; u16 s[8]; };
union U2 { uint2 u; u16 s[4]; };

static __device__ __forceinline__ u16 f2b(float f){
  union { __hip_bfloat16 h; u16 u; } cv; cv.h = __float2bfloat16(f); return cv.u;
}
static __device__ __forceinline__ float b2f(u16 v){
  union { __hip_bfloat16 h; u16 u; } cv; cv.u = v; return __bfloat162float(cv.h);
}
static __device__ __forceinline__ float fsig(float x){
  return __builtin_amdgcn_rcpf(1.0f + __expf(-x));
}
static __device__ __forceinline__ float ftanh(float x){
  float ax = fabsf(x);
  float t  = __expf(-2.0f*ax);
  float r  = (1.0f - t) * __builtin_amdgcn_rcpf(1.0f + t);
  return copysignf(r, x);
}

struct PrepArgs {
  const float* wx[4]; const float* wh[4];
  const float* wxb[4]; const float* whb[4];
};

// ---------------------------------------------------------------- k_prep ----
// Pack W rows in jp-interleaved order: row jp -> W_{gate=jp&3}[hc=jp>>2][k].
// B-frag: lane l holds W[jb*16+(l&15)][kb*32+(l>>4)*8+e].
__global__ void k_prep(PrepArgs P, u16* __restrict__ WxP, u16* __restrict__ WhP,
                       float* __restrict__ biasj)
{
  int sIdx = blockIdx.x*256 + threadIdx.x;          // 32768 frag slots
  int lane = sIdx & 63, kb = (sIdx>>6)&7, jb = sIdx>>9;
  int jp = jb*16 + (lane & 15);
  int gate = jp & 3, hc = jp >> 2;
  int kbase = kb*32 + ((lane>>4)<<3);
  const float* wx = P.wx[gate];
  const float* wh = P.wh[gate];
  U4 ox, oh;
  #pragma unroll
  for (int e=0; e<8; e++){
    ox.s[e] = f2b(wx[hc*256 + kbase + e]);
    oh.s[e] = f2b(wh[hc*256 + kbase + e]);
  }
  *(uint4*)(WxP + (size_t)sIdx*8) = ox.u;
  *(uint4*)(WhP + (size_t)sIdx*8) = oh.u;
  if (sIdx < 1024){
    int g2 = sIdx & 3, h2 = sIdx >> 2;
    biasj[sIdx] = P.wxb[g2][h2] + P.whb[g2][h2];
  }
}

// --------------------------------------------------------------- k_convx ----
// x[b][s][d] f32 -> xbf[s][b][d] bf16, 8 elems (16B) per thread, swizzled dest.
__global__ void k_convx(const float* __restrict__ x, u16* __restrict__ xbf)
{
  int tid = blockIdx.x*256 + threadIdx.x;           // 4,194,304 threads
  int ch = tid & 31;                                // d-chunk (8 elems)
  int b  = (tid>>5) & 255;
  int s  = tid >> 13;
  const float* src = x + ((size_t)b*512 + s)*256 + ch*8;
  float4 f0 = *(const float4*)(src);
  float4 f1 = *(const float4*)(src + 4);
  U4 o;
  o.s[0]=f2b(f0.x); o.s[1]=f2b(f0.y); o.s[2]=f2b(f0.z); o.s[3]=f2b(f0.w);
  o.s[4]=f2b(f1.x); o.s[5]=f2b(f1.y); o.s[6]=f2b(f1.z); o.s[7]=f2b(f1.w);
  u32 byteoff = (u32)(s*256 + b)*512u + (((u32)ch*16u) ^ ((u32)(b&7)<<4));
  *(uint4*)((char*)xbf + byteoff) = o.u;
}

// -------------------------------------------------------------- k_gemm_x ----
// Block: 128 rows (one s, half the batches) x 256 jp-cols (one quarter), K=256.
// 8 waves (2m x 4n), each wave 64x64, acc 4x4 frags. Epilogue writes xcat
// blobs laid out exactly per-(k_lstm thread): one uint4 per lstm-thread-step.
__launch_bounds__(512)
__global__ void k_gemm_x(const u16* __restrict__ xbf, const u16* __restrict__ WxP,
                         const float* __restrict__ biasj,
                         const float* __restrict__ bgg, const float* __restrict__ bii,
                         const float* __restrict__ bff, const float* __restrict__ boo,
                         u16* __restrict__ xcat)
{
  __shared__ u16 smA[128*256];                       // 64 KB, swizzled layout
  int tid = threadIdx.x;
  int bid = blockIdx.x;                              // 4096
  int mt = bid >> 2, jt = bid & 3;                   // jt = jp-quarter
  int s = mt >> 1, b0 = (mt & 1)*128;

  const uint4* srcA = (const uint4*)(xbf + (size_t)(s*256 + b0)*256);
  uint4* dstA = (uint4*)smA;
  #pragma unroll
  for (int i=0; i<8; i++) dstA[tid + i*512] = srcA[tid + i*512];
  __syncthreads();

  int lane = tid & 63, wid = tid >> 6;
  int wm = wid >> 2, wn = wid & 3;
  int r16 = lane & 15, khi = lane >> 4;

  f32x4 acc[4][4] = {};
  #pragma unroll
  for (int kb=0; kb<8; kb++){
    bf16x8 a[4];
    #pragma unroll
    for (int mb=0; mb<4; mb++){
      int row = wm*64 + mb*16 + r16;
      u32 abyte = (u32)row*512u + ((u32)((kb*32 + khi*8)*2) ^ ((u32)(row&7)<<4));
      U4 t; t.u = *(const uint4*)((const char*)smA + abyte);
      a[mb] = t.b;
    }
    #pragma unroll
    for (int nb=0; nb<4; nb++){
      int jbg = jt*16 + wn*4 + nb;
      U4 t; t.u = *(const uint4*)(WxP + (size_t)((jbg*8 + kb)*64 + lane)*8);
      #pragma unroll
      for (int mb=0; mb<4; mb++)
        acc[mb][nb] = __builtin_amdgcn_mfma_f32_16x16x32_bf16(a[mb], t.b, acc[mb][nb], 0,0,0);
    }
  }

  int gate = r16 & 3;
  const float* bb = (gate==0) ? bgg : (gate==1) ? bii : (gate==2) ? bff : boo;
  #pragma unroll
  for (int nb=0; nb<4; nb++){
    int jp = jt*256 + wn*64 + nb*16 + r16;
    int hc = jp >> 2;
    float bj = biasj[jp];
    int w_l = wn*2 + (nb>>1);
    int sub = nb & 1;
    #pragma unroll
    for (int mb=0; mb<4; mb++){
      int grp = (b0>>4) + wm*4 + mb;
      U2 pk;
      #pragma unroll
      for (int r=0; r<4; r++){
        int b = b0 + wm*64 + mb*16 + khi*4 + r;
        pk.s[r] = f2b(acc[mb][nb][r] + bj + bb[b*256 + hc]);
      }
      size_t idx = (((size_t)s*16 + grp)*4 + jt)*4096
                 + (size_t)(w_l*64 + khi*16 + r16)*8 + sub*4;
      *(uint2*)(xcat + idx) = pk.u;
    }
  }
}

// ---------------------------------------------------------------- k_lstm ----
// 64 blocks x 512 thr. grp = batch-group (16 batches), cb = jp-quarter.
// Wave w owns jp [cb*256+w*32, +32): weights in 64 VGPRs. h[16][256] in LDS
// (dbuf, swizzled); cross-block h exchange via hx + atomic counter barrier.
__launch_bounds__(512, 2)
__global__ void k_lstm(const u16* __restrict__ xcat2, const u16* __restrict__ WhP,
                       u16* __restrict__ hx, int* __restrict__ cnt,
                       float* __restrict__ hfin)
{
  __shared__ u16 hA[2][4096];                        // [par][b16][hc256] swz
  int tid = threadIdx.x, lane = tid & 63, w = tid >> 6;
  int bid = blockIdx.x;
  int xcd = bid & 7, slot = bid >> 3;
  int grp = xcd*2 + (slot>>2), cb = slot & 3;        // same-XCD groups (perf)
  int r16 = lane & 15, khi = lane >> 4;
  int gate = r16 & 3, hcl = r16 >> 2;

  // weights -> VGPRs (once)
  bf16x8 wreg[2][8];
  #pragma unroll
  for (int nb=0; nb<2; nb++){
    int jb16 = cb*16 + w*2 + nb;
    #pragma unroll
    for (int kb=0; kb<8; kb++){
      U4 t; t.u = *(const uint4*)(WhP + (size_t)((jb16*8 + kb)*64 + lane)*8);
      wreg[nb][kb] = t.b;
    }
  }

  for (int i=tid; i<4096; i+=512) hA[0][i] = 0;      // h0 = 0
  __syncthreads();

  const u16* xbase = xcat2 + ((size_t)grp*4 + cb)*4096 + (size_t)tid*8;
  U4 xr; xr.u = *(const uint4*)(xbase);              // step-0 blob

  float c[2][4] = {};

  for (int t=0; t<512; t++){
    int par = t & 1;
    int tn = (t < 511) ? t+1 : 511;
    U4 xn; xn.u = *(const uint4*)(xbase + (size_t)tn*262144);  // prefetch t+1

    // recurrent GEMM: acc[nb] over K=256 from LDS h
    f32x4 acc[2] = {};
    #pragma unroll
    for (int kb=0; kb<8; kb++){
      u32 ab = (u32)r16*512u + (((u32)(kb*64 + khi*16)) ^ ((u32)(r16&7)<<4));
      U4 ta; ta.u = *(const uint4*)((const char*)hA[par] + ab);
      acc[0] = __builtin_amdgcn_mfma_f32_16x16x32_bf16(ta.b, wreg[0][kb], acc[0], 0,0,0);
      acc[1] = __builtin_amdgcn_mfma_f32_16x16x32_bf16(ta.b, wreg[1][kb], acc[1], 0,0,0);
    }

    u16* hxN = hx + (size_t)(((t+1)&1)*16 + grp)*4096;

    #pragma unroll
    for (int nb=0; nb<2; nb++){
      int hc = cb*64 + w*8 + nb*4 + hcl;
      #pragma unroll
      for (int r=0; r<4; r++){
        float v = acc[nb][r] + b2f(xr.s[nb*4+r]);
        float a = (gate==0) ? ftanh(v) : fsig(v);
        float gi = a * __shfl_xor(a, 1);              // tanh(g)*sig(i) on gate0
        float fv = __shfl_xor(a, 2);                  // sig(f)
        float ov = __shfl_xor(a, 3);                  // sig(o)
        float cn = gi + c[nb][r]*fv;
        c[nb][r] = cn;
        float hv = ftanh(cn)*ov;
        if (gate == 0){
          u16 hb16 = f2b(hv);
          int b = khi*4 + r;
          hxN[b*256 + hc] = hb16;                     // for sibling blocks
          *(u16*)((char*)hA[par^1] +
                  ((u32)b*512u + (((u32)hc*2u) ^ ((u32)(b&7)<<4)))) = hb16;
          if (t == 511) hfin[(grp*16 + b)*256 + hc] = hv;
        }
      }
    }

    __syncthreads();                                  // all h stores issued+done
    if (tid == 0){
      int* cc = cnt + grp*2 + ((t+1)&1);
      __hip_atomic_fetch_add(cc, 1, __ATOMIC_RELEASE, __HIP_MEMORY_SCOPE_AGENT);
      int tgt = 4*((t>>1) + 1);
      while (__hip_atomic_load(cc, __ATOMIC_ACQUIRE, __HIP_MEMORY_SCOPE_AGENT) < tgt)
        __builtin_amdgcn_s_sleep(1);
    }
    __syncthreads();
    // fill other 3 blocks' h slices into LDS
    if (tid < 384){
      int oc = tid >> 7, rem = tid & 127;
      int b = rem >> 3, hc8 = rem & 7;
      int cbo = (cb + 1 + oc) & 3;
      int hc = cbo*64 + hc8*8;
      U4 tv; tv.u = *(const uint4*)(hxN + b*256 + hc);
      *(uint4*)((char*)hA[par^1] +
                ((u32)b*512u + (((u32)hc*2u) ^ ((u32)(b&7)<<4)))) = tv.u;
    }
    __syncthreads();
    xr = xn;
  }
}

// ---------------------------------------------------------------- k_proj ----
__global__ void k_proj(const float* __restrict__ hfin, const float* __restrict__ Wph_w,
                       const float* __restrict__ Wph_b, const float* __restrict__ bp,
                       float* __restrict__ out)
{
  __shared__ float hrow[256];
  __shared__ float pbuf[128];
  int b = blockIdx.x, tid = threadIdx.x;             // 128 threads
  hrow[tid]       = hfin[b*256 + tid];
  hrow[tid + 128] = hfin[b*256 + 128 + tid];
  __syncthreads();
  const float* wr = Wph_w + (size_t)tid*256;
  float acc = Wph_b[tid] + bp[b*128 + tid];
  #pragma unroll 8
  for (int k=0; k<256; k++) acc += hrow[k]*wr[k];
  pbuf[tid] = acc;
  __syncthreads();
  float mx = -1e30f;
  for (int i=0; i<128; i++) mx = fmaxf(mx, pbuf[i]);
  float e = __expf(acc - mx);
  __syncthreads();
  pbuf[tid] = e;
  __syncthreads();
  float sum = 0.f;
  for (int i=0; i<128; i++) sum += pbuf[i];
  out[b*128 + tid] = e / sum;
}

// ----------------------------------------------------------------- launch ----
extern "C" void kernel_launch(void* const* d_in, const int* in_sizes, int n_in,
                              void* d_out, int out_size, void* d_ws, size_t ws_size,
                              hipStream_t stream)
{
  (void)in_sizes; (void)n_in; (void)out_size; (void)ws_size;
  const float* x     = (const float*)d_in[0];
  const float* Wph_w = (const float*)d_in[17];
  const float* Wph_b = (const float*)d_in[18];
  const float* bg    = (const float*)d_in[19];
  const float* bi    = (const float*)d_in[20];
  const float* bf    = (const float*)d_in[21];
  const float* bo    = (const float*)d_in[22];
  const float* bp    = (const float*)d_in[23];

  PrepArgs P;
  for (int g=0; g<4; g++){
    P.wx[g]  = (const float*)d_in[1 + 4*g];
    P.wxb[g] = (const float*)d_in[2 + 4*g];
    P.wh[g]  = (const float*)d_in[3 + 4*g];
    P.whb[g] = (const float*)d_in[4 + 4*g];
  }

  char* ws = (char*)d_ws;
  u16*   xcat  = (u16*)(ws);                                   // 268435456 B
  u16*   xbf   = (u16*)(ws + 268435456);                       //  67108864 B (freed after k_gemm_x)
  u16*   hx    = (u16*)(ws + 268435456);                       //    262144 B (reuses xbf region)
  int*   cnt   = (int*)(ws + 268435456 + 262144);              //       128 B
  u16*   WxP   = (u16*)(ws + 268435456 + 67108864);            //    524288 B
  u16*   WhP   = (u16*)(ws + 268435456 + 67108864 + 524288);   //    524288 B
  float* biasj = (float*)(ws + 268435456 + 67108864 + 1048576);//      4096 B
  float* hfin  = (float*)(ws + 268435456 + 67108864 + 1048576 + 4096); // 262144 B

  k_prep <<<128,   256, 0, stream>>>(P, WxP, WhP, biasj);
  k_convx<<<16384, 256, 0, stream>>>(x, xbf);
  k_gemm_x<<<4096, 512, 0, stream>>>(xbf, WxP, biasj, bg, bi, bf, bo, xcat);
  hipMemsetAsync(cnt, 0, 128, stream);               // after xbf no longer needed
  k_lstm <<<64,    512, 0, stream>>>(xcat, WhP, hx, cnt, hfin);
  k_proj <<<256,   128, 0, stream>>>(hfin, Wph_w, Wph_b, bp, (float*)d_out);
}